// Round 5
// baseline (216.735 us; speedup 1.0000x reference)
//
#include <hip/hip_runtime.h>

typedef unsigned int u32;
typedef int i32x4 __attribute__((ext_vector_type(4)));

#define DIN 2048              // K elements; int8 row = 2048 bytes
#define DOUT 8192
#define MROWS 8192            // B*S
#define NELEM_W (8192 * 2048)

// workspace layout (bytes)
#define WS_PART 0                        // double[2048]
#define WS_WFAC 16384                    // float
#define WS_ROWFAC 16640                  // float[8192]
#define WS_XQ 49408                      // int8[8192*2048]
#define WS_WQ (49408 + 16777216)         // int8[8192*2048]

// ---------------- weight abs-sum (stage 1) ----------------------------------
__global__ void k_wabs(const float* __restrict__ w, double* __restrict__ part) {
    const float4* w4 = (const float4*)w;
    const unsigned t = threadIdx.x, b = blockIdx.x;
    float s = 0.f;
    for (unsigned i = b * 256u + t; i < (NELEM_W / 4); i += 2048u * 256u) {
        float4 v = w4[i];
        s += fabsf(v.x) + fabsf(v.y) + fabsf(v.z) + fabsf(v.w);
    }
    double d = (double)s;
    #pragma unroll
    for (int o = 32; o; o >>= 1) d += __shfl_down(d, o);
    __shared__ double red[4];
    if ((t & 63u) == 0u) red[t >> 6] = d;
    __syncthreads();
    if (t == 0) part[b] = red[0] + red[1] + red[2] + red[3];
}

// ---------------- weight abs-mean (stage 2) ---------------------------------
__global__ void k_wfin(const double* __restrict__ part, float* __restrict__ wfac) {
    const int t = threadIdx.x;
    double s = 0.0;
    #pragma unroll
    for (int j = 0; j < 8; ++j) s += part[t + j * 256];
    #pragma unroll
    for (int o = 32; o; o >>= 1) s += __shfl_down(s, o);
    __shared__ double red[4];
    if ((t & 63) == 0) red[t >> 6] = s;
    __syncthreads();
    if (t == 0) {
        double mean = (red[0] + red[1] + red[2] + red[3]) * (1.0 / (double)NELEM_W);
        *wfac = fmaxf((float)mean, 1e-5f);
    }
}

// ---------------- fused: ternary weight quant + RMS-norm/act quant ----------
__global__ void k_prep(const float* __restrict__ w, const float* __restrict__ wfac,
                       u32* __restrict__ wq, const float* __restrict__ x,
                       u32* __restrict__ xq, float* __restrict__ rowfac) {
    const int t = threadIdx.x;
    if (blockIdx.x < 2048) {
        const float scale = 1.0f / *wfac;
        const float4* w4 = (const float4*)w;
        for (unsigned i = blockIdx.x * 256u + t; i < (NELEM_W / 4); i += 2048u * 256u) {
            float4 v = w4[i];
            int q0 = (int)fminf(fmaxf(rintf(v.x * scale), -1.f), 1.f);
            int q1 = (int)fminf(fmaxf(rintf(v.y * scale), -1.f), 1.f);
            int q2 = (int)fminf(fmaxf(rintf(v.z * scale), -1.f), 1.f);
            int q3 = (int)fminf(fmaxf(rintf(v.w * scale), -1.f), 1.f);
            wq[i] = (u32)(q0 & 255) | ((u32)(q1 & 255) << 8) |
                    ((u32)(q2 & 255) << 16) | ((u32)(q3 & 255) << 24);
        }
        return;
    }
    const int row = blockIdx.x - 2048;
    const float4* xr = (const float4*)(x + (size_t)row * DIN);
    float4 v0 = xr[t], v1 = xr[t + 256];
    float ss = v0.x * v0.x + v0.y * v0.y + v0.z * v0.z + v0.w * v0.w
             + v1.x * v1.x + v1.y * v1.y + v1.z * v1.z + v1.w * v1.w;
    __shared__ float red[4];
    #pragma unroll
    for (int o = 32; o; o >>= 1) ss += __shfl_down(ss, o);
    if ((t & 63) == 0) red[t >> 6] = ss;
    __syncthreads();
    ss = red[0] + red[1] + red[2] + red[3];
    const float r = 1.0f / sqrtf(ss * (1.0f / DIN) + 1.1920929e-7f);
    float xn[8] = {v0.x * r, v0.y * r, v0.z * r, v0.w * r,
                   v1.x * r, v1.y * r, v1.z * r, v1.w * r};
    float am = 0.f;
    #pragma unroll
    for (int j = 0; j < 8; ++j) am = fmaxf(am, fabsf(xn[j]));
    __syncthreads();
    #pragma unroll
    for (int o = 32; o; o >>= 1) am = fmaxf(am, __shfl_down(am, o));
    if ((t & 63) == 0) red[t >> 6] = am;
    __syncthreads();
    am = fmaxf(fmaxf(red[0], red[1]), fmaxf(red[2], red[3]));
    const float amc = fmaxf(am, 1e-5f);
    const float s = 127.0f / amc;
    int q[8];
    #pragma unroll
    for (int j = 0; j < 8; ++j)
        q[j] = (int)fminf(fmaxf(rintf(xn[j] * s), -128.f), 127.f);
    u32* xo = xq + (size_t)row * (DIN / 4);
    xo[t] = (u32)(q[0] & 255) | ((u32)(q[1] & 255) << 8) |
            ((u32)(q[2] & 255) << 16) | ((u32)(q[3] & 255) << 24);
    xo[t + 256] = (u32)(q[4] & 255) | ((u32)(q[5] & 255) << 8) |
                  ((u32)(q[6] & 255) << 16) | ((u32)(q[7] & 255) << 24);
    if (t == 0) rowfac[row] = amc * (1.0f / 127.0f);
}

// ---------------- 256x256 int8 GEMM: m201 8-phase, 2-tile-deep prefetch -----
// LDS: A[slot][kh][256 rows][64B] at 0, B same at +65536 (slot stride 32768,
// kh stride 16384). 16B-granule XOR-(row&3) swizzle; inverse applied to the
// per-lane GLOBAL source (gload_lds writes linearly, rule #21).
// Per phase: {4-8 ds_read_b128 ; stage 1 half-tile (2 gload_lds, 2 tiles
// ahead) ; [ph4/ph8: vmcnt(6)] ; s_barrier ; lgkmcnt(0) ; setprio(1) ;
// 16 MFMA ; setprio(0) ; s_barrier}.  Gates verified by FIFO count:
// vmcnt(6) at ph4 -> tile T+1 fully resident; at ph8 -> tile T+2 resident.
__launch_bounds__(512, 2)
__global__ void k_gemm(const char* __restrict__ A, const char* __restrict__ Bw,
                       const float* __restrict__ rowfac, const float* __restrict__ wfac,
                       float* __restrict__ out) {
    __shared__ __attribute__((aligned(16))) char smb[131072];

    const int t = threadIdx.x;
    const int l = t & 63, w = t >> 6;
    const int wm = w >> 2, wn = w & 3;
    const int lr = l & 15, lc = l >> 4;
    // read: lane fragment byte offset within a [256][64B] half-buffer
    const int laneRd = lr * 64 + ((lc ^ (lr & 3)) * 16);
    // stage: thread t writes LDS linear j*8192 + t*16 = (row = j*128 + t/4,
    // gphys = t&3); source logical granule = gphys ^ (row&3)
    const int srow2 = t >> 2;
    const int sglog = ((t & 3) ^ (srow2 & 3)) * 16;

    // XCD-bijective block swizzle (1024 % 8 == 0)
    const int bid = blockIdx.x;
    const int wg = (bid & 7) * 128 + (bid >> 3);
    const int bm = wg >> 5, bn = wg & 31;
    const char* Ab = A + (size_t)(bm * 256) * DIN;
    const char* Bb = Bw + (size_t)(bn * 256) * DIN;

    i32x4 acc[8][4] = {};
    i32x4 fa[4], fb[4];

// stage one half-tile: operand base gbase, LDS op offset, tile byte-offset tB,
// K-half kh, slot s
#define STG1(gbase, opOff, tB, kh, s) do {                                        \
    _Pragma("unroll")                                                             \
    for (int j_ = 0; j_ < 2; ++j_)                                                \
        __builtin_amdgcn_global_load_lds(                                         \
            (const __attribute__((address_space(1))) void*)((gbase) + (size_t)(j_ * 128 + srow2) * DIN + (tB) + (kh) * 64 + sglog), \
            (__attribute__((address_space(3))) void*)(smb + (opOff) + (s) * 32768 + (kh) * 16384 + j_ * 8192 + t * 16), \
            16, 0, 0);                                                            \
} while (0)

#define NOGATE ((void)0)
#define VM6 asm volatile("s_waitcnt vmcnt(6)" ::: "memory")
#define VM0 asm volatile("s_waitcnt vmcnt(0)" ::: "memory")
#define NOSTG ((void)0)

#define PHASE(s, kh, mB, LOADB, STAGE_STMT, GATE_STMT) do {                       \
    const char* hbA_ = smb + (s) * 32768 + (kh) * 16384;                          \
    const char* hbB_ = hbA_ + 65536;                                              \
    _Pragma("unroll")                                                             \
    for (int i_ = 0; i_ < 4; ++i_)                                                \
        fa[i_] = *(const i32x4*)(hbA_ + (wm * 128 + ((mB) + i_) * 16) * 64 + laneRd); \
    if (LOADB) {                                                                  \
        _Pragma("unroll")                                                         \
        for (int n_ = 0; n_ < 4; ++n_)                                            \
            fb[n_] = *(const i32x4*)(hbB_ + (wn * 64 + n_ * 16) * 64 + laneRd);   \
    }                                                                             \
    STAGE_STMT;                                                                   \
    GATE_STMT;                                                                    \
    __builtin_amdgcn_s_barrier();                                                 \
    asm volatile("s_waitcnt lgkmcnt(0)" ::: "memory");                            \
    __builtin_amdgcn_s_setprio(1);                                                \
    _Pragma("unroll")                                                             \
    for (int m_ = 0; m_ < 4; ++m_)                                                \
        _Pragma("unroll")                                                         \
        for (int n_ = 0; n_ < 4; ++n_)                                            \
            acc[(mB) + m_][n_] = __builtin_amdgcn_mfma_i32_16x16x64_i8(           \
                fa[m_], fb[n_], acc[(mB) + m_][n_], 0, 0, 0);                     \
    __builtin_amdgcn_s_setprio(0);                                                \
    __builtin_amdgcn_s_barrier();                                                 \
} while (0)

    // prologue: tile0 (4 halves) + tile1's first 3 halves; gate tile0
    STG1(Ab, 0,     0,   0, 0);
    STG1(Bb, 65536, 0,   0, 0);
    STG1(Ab, 0,     0,   1, 0);
    STG1(Bb, 65536, 0,   1, 0);
    STG1(Bb, 65536, 128, 0, 1);
    STG1(Ab, 0,     128, 0, 1);
    STG1(Bb, 65536, 128, 1, 1);
    VM6;
    __builtin_amdgcn_s_barrier();

    #pragma unroll 1
    for (int it = 0; it < 7; ++it) {
        const int tB = it * 256;  // tile T=2*it byte offset; T+1=+128, T+2=+256, T+3=+384
        PHASE(0, 0, 0, true,  STG1(Ab, 0,     tB + 128, 1, 1), NOGATE); // ph1
        PHASE(0, 0, 4, false, STG1(Bb, 65536, tB + 256, 0, 0), NOGATE); // ph2
        PHASE(0, 1, 0, true,  STG1(Ab, 0,     tB + 256, 0, 0), NOGATE); // ph3
        PHASE(0, 1, 4, false, STG1(Bb, 65536, tB + 256, 1, 0), VM6);    // ph4
        PHASE(1, 0, 0, true,  STG1(Ab, 0,     tB + 256, 1, 0), NOGATE); // ph5
        PHASE(1, 0, 4, false, STG1(Bb, 65536, tB + 384, 0, 1), NOGATE); // ph6
        PHASE(1, 1, 0, true,  STG1(Ab, 0,     tB + 384, 0, 1), NOGATE); // ph7
        PHASE(1, 1, 4, false, STG1(Bb, 65536, tB + 384, 1, 1), VM6);    // ph8
    }
    // peeled last iteration (tiles 14, 15): only A(15,kh1) remains to stage
    PHASE(0, 0, 0, true,  STG1(Ab, 0, 1920, 1, 1), NOGATE);
    PHASE(0, 0, 4, false, NOSTG, NOGATE);
    PHASE(0, 1, 0, true,  NOSTG, NOGATE);
    PHASE(0, 1, 4, false, NOSTG, VM0);
    PHASE(1, 0, 0, true,  NOSTG, NOGATE);
    PHASE(1, 0, 4, false, NOSTG, NOGATE);
    PHASE(1, 1, 0, true,  NOSTG, NOGATE);
    PHASE(1, 1, 4, false, NOSTG, NOGATE);

    // epilogue: exact int32 -> fp32, dequant scales, store
    const float wf = *wfac;
    const int c0 = bn * 256 + wn * 64 + lr;
    #pragma unroll
    for (int m = 0; m < 8; ++m) {
        #pragma unroll
        for (int r = 0; r < 4; ++r) {
            const int grow = bm * 256 + wm * 128 + m * 16 + lc * 4 + r;
            const float s = rowfac[grow] * wf;
            const size_t ob = (size_t)grow * DOUT + c0;
            #pragma unroll
            for (int n = 0; n < 4; ++n)
                out[ob + n * 16] = (float)acc[m][n][r] * s;
        }
    }
#undef STG1
#undef PHASE
#undef NOGATE
#undef VM6
#undef VM0
#undef NOSTG
}

extern "C" void kernel_launch(void* const* d_in, const int* in_sizes, int n_in,
                              void* d_out, int out_size, void* d_ws, size_t ws_size,
                              hipStream_t stream) {
    const float* x = (const float*)d_in[0];   // [4,2048,2048]
    const float* wt = (const float*)d_in[1];  // [8192,2048]
    float* out = (float*)d_out;               // [4,2048,8192] fp32
    char* ws = (char*)d_ws;

    double* part = (double*)(ws + WS_PART);
    float* wfac = (float*)(ws + WS_WFAC);
    float* rowfac = (float*)(ws + WS_ROWFAC);
    u32* xq = (u32*)(ws + WS_XQ);
    u32* wq = (u32*)(ws + WS_WQ);

    k_wabs<<<2048, 256, 0, stream>>>(wt, part);
    k_wfin<<<1, 256, 0, stream>>>(part, wfac);
    k_prep<<<2048 + MROWS, 256, 0, stream>>>(wt, wfac, wq, x, xq, rowfac);
    k_gemm<<<1024, 512, 0, stream>>>((const char*)xq, (const char*)wq, rowfac, wfac, out);
}